// Round 7
// baseline (148.321 us; speedup 1.0000x reference)
//
#include <hip/hip_runtime.h>
#include <hip/hip_bf16.h>
#include <math.h>

// Problem constants
#define NB   2
#define CC   256
#define HH   128
#define WW   128
#define HPP  130
#define WPP  130
#define LQ   16384   // HH*WW

typedef __attribute__((ext_vector_type(8))) short short8;
typedef __attribute__((ext_vector_type(4))) float f32x4;
typedef __attribute__((ext_vector_type(4))) unsigned int u32x4;

static __device__ __forceinline__ unsigned short f2bf(float f) {
    __hip_bfloat16 h = __float2bfloat16(f);
    return __builtin_bit_cast(unsigned short, h);
}

// branch-free tanh-form GELU: x * sigmoid(1.5957691*(x + 0.044715 x^3))
static __device__ __forceinline__ float gelu_fast(float x) {
    float u = x * x;
    float t = x * fmaf(0.044715f, u, 1.0f);
    float e = __builtin_amdgcn_exp2f(t * 2.3022083f);
    float r = __builtin_amdgcn_rcpf(e + 1.0f);
    return x - x * r;
}

// -------------------------------------------------------------------------
// Kernel A: merged weight prep.
// -------------------------------------------------------------------------
__global__ __launch_bounds__(256) void prep_kernel(
    const float* __restrict__ dwk,
    const float* __restrict__ Wval,
    const float* __restrict__ Wout,
    const float* __restrict__ Woff, const float* __restrict__ boff,
    const float* __restrict__ Wattn, const float* __restrict__ battn,
    float* __restrict__ kt,
    unsigned short* __restrict__ wt_val,
    unsigned short* __restrict__ wt_out,
    unsigned short* __restrict__ wt_oa,
    float* __restrict__ b_oa)
{
    int b = blockIdx.x;
    int t = threadIdx.x;
    if (b < 49) {
        kt[b * CC + t] = dwk[t * 49 + b];
    } else if (b < 305) {
        int k = b - 49;
        wt_val[(size_t)t * 256 + k] = f2bf(Wval[(size_t)k * 256 + t]);
    } else if (b < 561) {
        int k = b - 305;
        wt_out[(size_t)t * 256 + k] = f2bf(Wout[(size_t)k * 256 + t]);
    } else {
        int k = b - 561;
        if (t < 128) {
            float v = 0.f, bb = 0.f;
            if (t < 64)      { v = Woff[(size_t)k * 64 + t];        bb = boff[t]; }
            else if (t < 96) { v = Wattn[(size_t)k * 32 + (t - 64)]; bb = battn[t - 64]; }
            wt_oa[(size_t)t * 256 + k] = f2bf(v);
            if (k == 0) b_oa[t] = bb;
        }
    }
}

// -------------------------------------------------------------------------
// Kernel B: zero only the border of v_pad (interior overwritten by GEMM)
// -------------------------------------------------------------------------
__global__ __launch_bounds__(256) void zero_border_kernel(float* __restrict__ vpad)
{
    int b = blockIdx.x;
    int n = (b >= 516) ? 1 : 0;
    int i = b - n * 516;
    int y, x;
    if (i < 130)      { y = 0;           x = i; }
    else if (i < 260) { y = 129;         x = i - 130; }
    else if (i < 388) { y = i - 260 + 1; x = 0; }
    else              { y = i - 388 + 1; x = 129; }
    vpad[(((size_t)n * HPP + y) * WPP + x) * CC + threadIdx.x] = 0.f;
}

// -------------------------------------------------------------------------
// Kernel 1: fused depthwise 7x7 conv + bias + channel-LN + GELU -> bf16
// lane = channel-quad (64 lanes x 4ch = 256 ch per wave), wave = 2 w-pos,
// block = 4 waves = 8 w-positions. LN reduce is intra-wave shuffles only.
// -------------------------------------------------------------------------
__global__ __launch_bounds__(256) void conv_ln_gelu_kernel(
    const float* __restrict__ q,      // (N, LQ, C)
    const float* __restrict__ kt,     // (49, C)
    const float* __restrict__ kbias,
    const float* __restrict__ lnw,
    const float* __restrict__ lnb,
    unsigned short* __restrict__ qact) // (N, LQ, C) bf16
{
    int t    = threadIdx.x;
    int lane = t & 63;
    int wv   = t >> 6;                // wave 0..3
    int c4   = lane << 2;             // channel base
    int w0   = blockIdx.x * 8;
    int h    = blockIdx.y;
    int n    = blockIdx.z;
    int p0   = w0 + wv * 2;           // this wave's first position

    const float* qn = q + (size_t)n * LQ * CC + c4;

    f32x4 bias4 = *(const f32x4*)(kbias + c4);
    f32x4 acc0 = bias4;
    f32x4 acc1 = bias4;

    if (w0 >= 8 && w0 <= 112 && h >= 3 && h <= 124) {
        // -------- interior: no bounds checks --------
        #pragma unroll
        for (int ky = 0; ky < 7; ++ky) {
            const float* qrow = qn + ((size_t)(h + ky - 3) * WW + (p0 - 3)) * CC;
            f32x4 wt[7];
            #pragma unroll
            for (int kx = 0; kx < 7; ++kx)
                wt[kx] = *(const f32x4*)(kt + (ky * 7 + kx) * CC + c4);
            f32x4 in[8];
            #pragma unroll
            for (int j = 0; j < 8; ++j)
                in[j] = *(const f32x4*)(qrow + (size_t)j * CC);
            #pragma unroll
            for (int kx = 0; kx < 7; ++kx) {
                acc0 += in[kx]     * wt[kx];
                acc1 += in[kx + 1] * wt[kx];
            }
        }
    } else {
        // -------- border: checked --------
        #pragma unroll
        for (int ky = 0; ky < 7; ++ky) {
            int iy = h + ky - 3;
            if (iy < 0 || iy >= HH) continue;
            const float* qrow = qn + (size_t)iy * WW * CC;
            f32x4 wt[7];
            #pragma unroll
            for (int kx = 0; kx < 7; ++kx)
                wt[kx] = *(const f32x4*)(kt + (ky * 7 + kx) * CC + c4);
            f32x4 in[8];
            #pragma unroll
            for (int j = 0; j < 8; ++j) {
                int ix = p0 - 3 + j;
                if (ix >= 0 && ix < WW)
                    in[j] = *(const f32x4*)(qrow + (size_t)ix * CC);
                else
                    in[j] = (f32x4){0.f, 0.f, 0.f, 0.f};
            }
            #pragma unroll
            for (int kx = 0; kx < 7; ++kx) {
                acc0 += in[kx]     * wt[kx];
                acc1 += in[kx + 1] * wt[kx];
            }
        }
    }

    // LayerNorm: per-thread partial over 4 channels, then 64-lane reduce
    float s0 = acc0[0] + acc0[1] + acc0[2] + acc0[3];
    float q0 = acc0[0]*acc0[0] + acc0[1]*acc0[1] + acc0[2]*acc0[2] + acc0[3]*acc0[3];
    float s1 = acc1[0] + acc1[1] + acc1[2] + acc1[3];
    float q1 = acc1[0]*acc1[0] + acc1[1]*acc1[1] + acc1[2]*acc1[2] + acc1[3]*acc1[3];
    #pragma unroll
    for (int m = 1; m < 64; m <<= 1) {
        s0 += __shfl_xor(s0, m);
        q0 += __shfl_xor(q0, m);
        s1 += __shfl_xor(s1, m);
        q1 += __shfl_xor(q1, m);
    }
    float mu0  = s0 * (1.0f / 256.0f);
    float var0 = q0 * (1.0f / 256.0f) - mu0 * mu0;
    float inv0 = rsqrtf(var0 + 1e-5f);
    float mu1  = s1 * (1.0f / 256.0f);
    float var1 = q1 * (1.0f / 256.0f) - mu1 * mu1;
    float inv1 = rsqrtf(var1 + 1e-5f);

    f32x4 lw = *(const f32x4*)(lnw + c4);
    f32x4 lb = *(const f32x4*)(lnb + c4);

    unsigned short* qo = qact + (((size_t)n * LQ) + (size_t)h * WW + p0) * CC + c4;
    ushort4 o0, o1;
    o0.x = f2bf(gelu_fast((acc0[0] - mu0) * inv0 * lw[0] + lb[0]));
    o0.y = f2bf(gelu_fast((acc0[1] - mu0) * inv0 * lw[1] + lb[1]));
    o0.z = f2bf(gelu_fast((acc0[2] - mu0) * inv0 * lw[2] + lb[2]));
    o0.w = f2bf(gelu_fast((acc0[3] - mu0) * inv0 * lw[3] + lb[3]));
    o1.x = f2bf(gelu_fast((acc1[0] - mu1) * inv1 * lw[0] + lb[0]));
    o1.y = f2bf(gelu_fast((acc1[1] - mu1) * inv1 * lw[1] + lb[1]));
    o1.z = f2bf(gelu_fast((acc1[2] - mu1) * inv1 * lw[2] + lb[2]));
    o1.w = f2bf(gelu_fast((acc1[3] - mu1) * inv1 * lw[3] + lb[3]));
    *reinterpret_cast<ushort4*>(qo)      = o0;
    *reinterpret_cast<ushort4*>(qo + CC) = o1;
}

// -------------------------------------------------------------------------
// Kernel 2a: merged value + oa GEMM (bf16 MFMA), grid.y: 0,1=val  2=oa
// -------------------------------------------------------------------------
__global__ __launch_bounds__(256) void gemm_val_oa(
    const unsigned short* __restrict__ A,
    const unsigned short* __restrict__ Bv, const float* __restrict__ bv_,
    float* __restrict__ Cv,
    const unsigned short* __restrict__ Bo, const float* __restrict__ bo_,
    float* __restrict__ Co)
{
    __shared__ unsigned short Al[128][72];
    __shared__ unsigned short Bl[128][72];

    bool oam = (blockIdx.y == 2);
    const unsigned short* Bt = oam ? Bo : Bv;
    const float* bias = oam ? bo_ : bv_;
    int bn = oam ? 0 : blockIdx.y * 128;

    int t    = threadIdx.x;
    int bm   = blockIdx.x * 128;
    int wid  = t >> 6;
    int lane = t & 63;
    int wr   = wid >> 1;
    int wc   = wid & 1;
    int lr   = lane & 15;
    int lg   = lane >> 4;

    int srow = t >> 1;
    int sseg = (t & 1) << 5;

    const unsigned short* gA = A + (size_t)(bm + srow) * 256 + sseg;
    const unsigned short* gB = Bt + (size_t)(bn + srow) * 256 + sseg;
    unsigned short* lA = &Al[srow][sseg];
    unsigned short* lB = &Bl[srow][sseg];

    f32x4 acc[4][4] = {};

    for (int kt = 0; kt < 4; ++kt) {
        const unsigned short* ga = gA + kt * 64;
        const unsigned short* gb = gB + kt * 64;
        u32x4 a0 = *(const u32x4*)(ga);
        u32x4 a1 = *(const u32x4*)(ga + 8);
        u32x4 a2 = *(const u32x4*)(ga + 16);
        u32x4 a3 = *(const u32x4*)(ga + 24);
        u32x4 b0 = *(const u32x4*)(gb);
        u32x4 b1 = *(const u32x4*)(gb + 8);
        u32x4 b2 = *(const u32x4*)(gb + 16);
        u32x4 b3 = *(const u32x4*)(gb + 24);
        *(u32x4*)(lA)      = a0;
        *(u32x4*)(lA + 8)  = a1;
        *(u32x4*)(lA + 16) = a2;
        *(u32x4*)(lA + 24) = a3;
        *(u32x4*)(lB)      = b0;
        *(u32x4*)(lB + 8)  = b1;
        *(u32x4*)(lB + 16) = b2;
        *(u32x4*)(lB + 24) = b3;
        __syncthreads();

        #pragma unroll
        for (int kk = 0; kk < 2; ++kk) {
            short8 af[4], bfr[4];
            #pragma unroll
            for (int m = 0; m < 4; ++m)
                af[m] = *(const short8*)(&Al[wr * 64 + m * 16 + lr][kk * 32 + lg * 8]);
            #pragma unroll
            for (int nn = 0; nn < 4; ++nn)
                bfr[nn] = *(const short8*)(&Bl[wc * 64 + nn * 16 + lr][kk * 32 + lg * 8]);
            #pragma unroll
            for (int m = 0; m < 4; ++m)
                #pragma unroll
                for (int nn = 0; nn < 4; ++nn)
                    acc[m][nn] = __builtin_amdgcn_mfma_f32_16x16x32_bf16(
                        af[m], bfr[nn], acc[m][nn], 0, 0, 0);
        }
        __syncthreads();
    }

    float bvv[4];
    #pragma unroll
    for (int nn = 0; nn < 4; ++nn) bvv[nn] = bias[bn + wc * 64 + nn * 16 + lr];

    #pragma unroll
    for (int m = 0; m < 4; ++m) {
        #pragma unroll
        for (int j = 0; j < 4; ++j) {
            int row = bm + wr * 64 + m * 16 + lg * 4 + j;
            size_t rbase;
            if (oam) {
                rbase = (size_t)row * 128;
            } else {
                int nb = row >> 14;
                int hw = row & 16383;
                int hh = hw >> 7;
                int ww = hw & 127;
                rbase = (((size_t)nb * HPP + (hh + 1)) * WPP + (ww + 1)) * CC;
            }
            float* C = oam ? Co : Cv;
            #pragma unroll
            for (int nn = 0; nn < 4; ++nn) {
                int col = bn + wc * 64 + nn * 16 + lr;
                C[rbase + col] = acc[m][nn][j] + bvv[nn];
            }
        }
    }
}

// -------------------------------------------------------------------------
// Kernel 2b: bf16 MFMA GEMM, row-major store (output GEMM)
// -------------------------------------------------------------------------
__global__ __launch_bounds__(256) void gemm_mfma_row(
    const unsigned short* __restrict__ A,
    const unsigned short* __restrict__ Bt,
    const float* __restrict__ bias,
    float* __restrict__ C,
    int Nn)
{
    __shared__ unsigned short Al[128][72];
    __shared__ unsigned short Bl[128][72];

    int t    = threadIdx.x;
    int bm   = blockIdx.x * 128;
    int bn   = blockIdx.y * 128;
    int wid  = t >> 6;
    int lane = t & 63;
    int wr   = wid >> 1;
    int wc   = wid & 1;
    int lr   = lane & 15;
    int lg   = lane >> 4;

    int srow = t >> 1;
    int sseg = (t & 1) << 5;

    const unsigned short* gA = A + (size_t)(bm + srow) * 256 + sseg;
    const unsigned short* gB = Bt + (size_t)(bn + srow) * 256 + sseg;
    unsigned short* lA = &Al[srow][sseg];
    unsigned short* lB = &Bl[srow][sseg];

    f32x4 acc[4][4] = {};

    for (int kt = 0; kt < 4; ++kt) {
        const unsigned short* ga = gA + kt * 64;
        const unsigned short* gb = gB + kt * 64;
        u32x4 a0 = *(const u32x4*)(ga);
        u32x4 a1 = *(const u32x4*)(ga + 8);
        u32x4 a2 = *(const u32x4*)(ga + 16);
        u32x4 a3 = *(const u32x4*)(ga + 24);
        u32x4 b0 = *(const u32x4*)(gb);
        u32x4 b1 = *(const u32x4*)(gb + 8);
        u32x4 b2 = *(const u32x4*)(gb + 16);
        u32x4 b3 = *(const u32x4*)(gb + 24);
        *(u32x4*)(lA)      = a0;
        *(u32x4*)(lA + 8)  = a1;
        *(u32x4*)(lA + 16) = a2;
        *(u32x4*)(lA + 24) = a3;
        *(u32x4*)(lB)      = b0;
        *(u32x4*)(lB + 8)  = b1;
        *(u32x4*)(lB + 16) = b2;
        *(u32x4*)(lB + 24) = b3;
        __syncthreads();

        #pragma unroll
        for (int kk = 0; kk < 2; ++kk) {
            short8 af[4], bfr[4];
            #pragma unroll
            for (int m = 0; m < 4; ++m)
                af[m] = *(const short8*)(&Al[wr * 64 + m * 16 + lr][kk * 32 + lg * 8]);
            #pragma unroll
            for (int nn = 0; nn < 4; ++nn)
                bfr[nn] = *(const short8*)(&Bl[wc * 64 + nn * 16 + lr][kk * 32 + lg * 8]);
            #pragma unroll
            for (int m = 0; m < 4; ++m)
                #pragma unroll
                for (int nn = 0; nn < 4; ++nn)
                    acc[m][nn] = __builtin_amdgcn_mfma_f32_16x16x32_bf16(
                        af[m], bfr[nn], acc[m][nn], 0, 0, 0);
        }
        __syncthreads();
    }

    float bvv[4];
    #pragma unroll
    for (int nn = 0; nn < 4; ++nn) bvv[nn] = bias[bn + wc * 64 + nn * 16 + lr];

    #pragma unroll
    for (int m = 0; m < 4; ++m) {
        #pragma unroll
        for (int j = 0; j < 4; ++j) {
            int row = bm + wr * 64 + m * 16 + lg * 4 + j;
            size_t rbase = (size_t)row * Nn;
            #pragma unroll
            for (int nn = 0; nn < 4; ++nn) {
                int col = bn + wc * 64 + nn * 16 + lr;
                C[rbase + col] = acc[m][nn][j] + bvv[nn];
            }
        }
    }
}

// -------------------------------------------------------------------------
// Kernel 3: deformable bilinear sampling + attention-weighted sum
// -------------------------------------------------------------------------
__global__ __launch_bounds__(256) void sampler_kernel(
    const float* __restrict__ rp,     // (N, LQ, 1, 2)
    const float* __restrict__ oa,     // (N*LQ, 128)
    const float* __restrict__ vpad,   // (N, HP, WP, C)
    unsigned short* __restrict__ outb) // (N*LQ, C) bf16
{
    __shared__ int4   sIdx[4][4][8];
    __shared__ float4 sW[4][4][8];

    int tid  = threadIdx.x;
    int row0 = blockIdx.x * 4;

    if (tid < 128) {
        int rl   = tid >> 5;
        int hp   = tid & 31;
        int head = hp >> 2;
        int p    = hp & 3;
        int row  = row0 + rl;

        float ref0 = rp[(size_t)row * 2 + 0];
        float ref1 = rp[(size_t)row * 2 + 1];
        float o0 = oa[(size_t)row * 128 + head * 8 + p * 2 + 0];
        float o1 = oa[(size_t)row * 128 + head * 8 + p * 2 + 1];
        float al = oa[(size_t)row * 128 + 64 + head * 4 + p];
        float a  = 1.0f / (1.0f + __builtin_amdgcn_exp2f(-al * 1.4426950409f));

        float gy = (float)(p >> 1);
        float gx = (float)(p & 1);
        float x = ref0 * WPP + gy + o0 - 0.5f;
        float y = ref1 * HPP + gx + o1 - 0.5f;

        float x0f = floorf(x), y0f = floorf(y);
        int   x0  = (int)x0f,  y0  = (int)y0f;
        float wx1 = x - x0f, wx0 = 1.f - wx1;
        float wy1 = y - y0f, wy0 = 1.f - wy1;
        int x1 = x0 + 1, y1 = y0 + 1;

        bool vx0 = (x0 >= 0) & (x0 < WPP);
        bool vx1 = (x1 >= 0) & (x1 < WPP);
        bool vy0 = (y0 >= 0) & (y0 < HPP);
        bool vy1 = (y1 >= 0) & (y1 < HPP);
        int cx0 = min(max(x0, 0), WPP - 1);
        int cx1 = min(max(x1, 0), WPP - 1);
        int cy0 = min(max(y0, 0), HPP - 1);
        int cy1 = min(max(y1, 0), HPP - 1);

        int4 id;
        id.x = cy0 * WPP + cx0;
        id.y = cy0 * WPP + cx1;
        id.z = cy1 * WPP + cx0;
        id.w = cy1 * WPP + cx1;
        float4 w;
        w.x = (vx0 && vy0) ? a * wx0 * wy0 : 0.f;
        w.y = (vx1 && vy0) ? a * wx1 * wy0 : 0.f;
        w.z = (vx0 && vy1) ? a * wx0 * wy1 : 0.f;
        w.w = (vx1 && vy1) ? a * wx1 * wy1 : 0.f;

        sIdx[rl][p][head] = id;
        sW[rl][p][head]   = w;
    }
    __syncthreads();

    int rl   = tid >> 6;
    int c0   = (tid & 63) * 4;
    int head = c0 >> 5;
    int row  = row0 + rl;
    int n    = row >> 14;
    const float* vbase = vpad + (size_t)n * HPP * WPP * CC + c0;

    float4 acc = make_float4(0.f, 0.f, 0.f, 0.f);
    #pragma unroll
    for (int p = 0; p < 4; ++p) {
        int4   id = sIdx[rl][p][head];
        float4 w  = sW[rl][p][head];
        float4 g0 = *reinterpret_cast<const float4*>(vbase + (size_t)id.x * CC);
        float4 g1 = *reinterpret_cast<const float4*>(vbase + (size_t)id.y * CC);
        float4 g2 = *reinterpret_cast<const float4*>(vbase + (size_t)id.z * CC);
        float4 g3 = *reinterpret_cast<const float4*>(vbase + (size_t)id.w * CC);
        acc.x += w.x * g0.x + w.y * g1.x + w.z * g2.x + w.w * g3.x;
        acc.y += w.x * g0.y + w.y * g1.y + w.z * g2.y + w.w * g3.y;
        acc.z += w.x * g0.z + w.y * g1.z + w.z * g2.z + w.w * g3.z;
        acc.w += w.x * g0.w + w.y * g1.w + w.z * g2.w + w.w * g3.w;
    }
    ushort4 o;
    o.x = f2bf(acc.x);
    o.y = f2bf(acc.y);
    o.z = f2bf(acc.z);
    o.w = f2bf(acc.w);
    *reinterpret_cast<ushort4*>(&outb[(size_t)row * CC + c0]) = o;
}

// -------------------------------------------------------------------------
extern "C" void kernel_launch(void* const* d_in, const int* in_sizes, int n_in,
                              void* d_out, int out_size, void* d_ws, size_t ws_size,
                              hipStream_t stream)
{
    const float* query = (const float*)d_in[0];
    const float* rp    = (const float*)d_in[1];
    const float* dwk   = (const float*)d_in[4];
    const float* dwb   = (const float*)d_in[5];
    const float* lnw   = (const float*)d_in[6];
    const float* lnb   = (const float*)d_in[7];
    const float* Woff  = (const float*)d_in[8];
    const float* boff  = (const float*)d_in[9];
    const float* Wattn = (const float*)d_in[10];
    const float* battn = (const float*)d_in[11];
    const float* Wval  = (const float*)d_in[12];
    const float* bval  = (const float*)d_in[13];
    const float* Wout  = (const float*)d_in[14];
    const float* bout  = (const float*)d_in[15];
    float* out = (float*)d_out;

    const int M = NB * LQ;  // 32768

    // workspace layout (bytes)
    uint8_t* w8 = (uint8_t*)d_ws;
    unsigned short* q_act  = (unsigned short*)w8;                    // 16,777,216
    float*          v_pad  = (float*)(w8 + 16777216);                // 34,611,200
    float*          oa     = (float*)(w8 + 51388416);                // 16,777,216
    unsigned short* wt_val = (unsigned short*)(w8 + 68165632);       //    131,072
    unsigned short* wt_out = (unsigned short*)(w8 + 68296704);       //    131,072
    unsigned short* wt_oa  = (unsigned short*)(w8 + 68427776);       //     65,536
    float*          b_oa   = (float*)(w8 + 68493312);                //        512
    float*          kt     = (float*)(w8 + 68493824);                //     50,176
    unsigned short* out_attn = q_act;  // alias: q_act dead after oa GEMM

    // border-only zeroing of v_pad (interior fully written by value GEMM)
    zero_border_kernel<<<1032, 256, 0, stream>>>(v_pad);

    // merged weight prep
    prep_kernel<<<817, 256, 0, stream>>>(
        dwk, Wval, Wout, Woff, boff, Wattn, battn,
        kt, wt_val, wt_out, wt_oa, b_oa);

    // conv + LN + GELU -> bf16 q_act
    {
        dim3 grid(WW / 8, HH, NB);
        conv_ln_gelu_kernel<<<grid, 256, 0, stream>>>(
            query, kt, dwb, lnw, lnb, q_act);
    }

    // value GEMM (padded layout) + oa GEMM, one launch
    {
        dim3 grid(M / 128, 3);
        gemm_val_oa<<<grid, 256, 0, stream>>>(
            q_act, wt_val, bval, v_pad, wt_oa, b_oa, oa);
    }

    // sampling + weighted sum -> bf16
    sampler_kernel<<<M / 4, 256, 0, stream>>>(rp, oa, v_pad, out_attn);

    // output GEMM -> d_out fp32
    {
        dim3 grid(M / 128, 2);
        gemm_mfma_row<<<grid, 256, 0, stream>>>(out_attn, wt_out, bout, out, 256);
    }
}

// Round 8
// 96.592 us; speedup vs baseline: 1.5355x; 1.5355x over previous
//
#include <hip/hip_runtime.h>
#include <hip/hip_bf16.h>
#include <math.h>

// Problem constants
#define NB   2
#define CC   256
#define HH   128
#define WW   128
#define HPP  130
#define WPP  130
#define LQ   16384   // HH*WW

typedef __attribute__((ext_vector_type(8))) short short8;
typedef __attribute__((ext_vector_type(4))) float f32x4;
typedef __attribute__((ext_vector_type(4))) unsigned int u32x4;

static __device__ __forceinline__ unsigned short f2bf(float f) {
    __hip_bfloat16 h = __float2bfloat16(f);
    return __builtin_bit_cast(unsigned short, h);
}
static __device__ __forceinline__ float bf2f(unsigned short u) {
    unsigned int x = ((unsigned int)u) << 16;
    return __builtin_bit_cast(float, x);
}

// branch-free tanh-form GELU: x * sigmoid(1.5957691*(x + 0.044715 x^3))
static __device__ __forceinline__ float gelu_fast(float x) {
    float u = x * x;
    float t = x * fmaf(0.044715f, u, 1.0f);
    float e = __builtin_amdgcn_exp2f(t * 2.3022083f);
    float r = __builtin_amdgcn_rcpf(e + 1.0f);
    return x - x * r;
}

// -------------------------------------------------------------------------
// Kernel A: merged weight prep.
// -------------------------------------------------------------------------
__global__ __launch_bounds__(256) void prep_kernel(
    const float* __restrict__ dwk,
    const float* __restrict__ Wval,
    const float* __restrict__ Wout,
    const float* __restrict__ Woff, const float* __restrict__ boff,
    const float* __restrict__ Wattn, const float* __restrict__ battn,
    float* __restrict__ kt,
    unsigned short* __restrict__ wt_val,
    unsigned short* __restrict__ wt_out,
    unsigned short* __restrict__ wt_oa,
    float* __restrict__ b_oa)
{
    int b = blockIdx.x;
    int t = threadIdx.x;
    if (b < 49) {
        kt[b * CC + t] = dwk[t * 49 + b];
    } else if (b < 305) {
        int k = b - 49;
        wt_val[(size_t)t * 256 + k] = f2bf(Wval[(size_t)k * 256 + t]);
    } else if (b < 561) {
        int k = b - 305;
        wt_out[(size_t)t * 256 + k] = f2bf(Wout[(size_t)k * 256 + t]);
    } else {
        int k = b - 561;
        if (t < 128) {
            float v = 0.f, bb = 0.f;
            if (t < 64)      { v = Woff[(size_t)k * 64 + t];        bb = boff[t]; }
            else if (t < 96) { v = Wattn[(size_t)k * 32 + (t - 64)]; bb = battn[t - 64]; }
            wt_oa[(size_t)t * 256 + k] = f2bf(v);
            if (k == 0) b_oa[t] = bb;
        }
    }
}

// -------------------------------------------------------------------------
// Kernel B: zero only the border of v_pad (interior overwritten by GEMM)
// -------------------------------------------------------------------------
__global__ __launch_bounds__(256) void zero_border_kernel(unsigned short* __restrict__ vpad)
{
    int b = blockIdx.x;
    int n = (b >= 516) ? 1 : 0;
    int i = b - n * 516;
    int y, x;
    if (i < 130)      { y = 0;           x = i; }
    else if (i < 260) { y = 129;         x = i - 130; }
    else if (i < 388) { y = i - 260 + 1; x = 0; }
    else              { y = i - 388 + 1; x = 129; }
    vpad[(((size_t)n * HPP + y) * WPP + x) * CC + threadIdx.x] = 0;
}

// -------------------------------------------------------------------------
// Kernel 1: fused depthwise 7x7 conv + bias + channel-LN + GELU -> bf16
// R6 known-good structure: thread = 1 channel x 8 w-positions, VGPR ~40.
// Interior blocks take a check-free path (83% of blocks).
// -------------------------------------------------------------------------
__global__ __launch_bounds__(256) void conv_ln_gelu_kernel(
    const float* __restrict__ q,      // (N, LQ, C)
    const float* __restrict__ kt,     // (49, C)
    const float* __restrict__ kbias,
    const float* __restrict__ lnw,
    const float* __restrict__ lnb,
    unsigned short* __restrict__ qact) // (N, LQ, C) bf16
{
    int c  = threadIdx.x;
    int w0 = blockIdx.x * 8;
    int h  = blockIdx.y;
    int n  = blockIdx.z;

    const float* qn = q + (size_t)n * LQ * CC + c;

    float bias = kbias[c];
    float acc[8];
    #pragma unroll
    for (int i = 0; i < 8; ++i) acc[i] = bias;

    if (w0 >= 8 && w0 <= 112 && h >= 3 && h <= 124) {
        // -------- interior: no bounds checks --------
        #pragma unroll
        for (int ky = 0; ky < 7; ++ky) {
            const float* qrow = qn + ((size_t)(h + ky - 3) * WW + (w0 - 3)) * CC;
            float wt[7];
            #pragma unroll
            for (int kx = 0; kx < 7; ++kx)
                wt[kx] = kt[(ky * 7 + kx) * CC + c];
            float in[14];
            #pragma unroll
            for (int j = 0; j < 14; ++j)
                in[j] = qrow[(size_t)j * CC];
            #pragma unroll
            for (int i = 0; i < 8; ++i)
                #pragma unroll
                for (int kx = 0; kx < 7; ++kx)
                    acc[i] = fmaf(in[i + kx], wt[kx], acc[i]);
        }
    } else {
        // -------- border: checked --------
        #pragma unroll
        for (int ky = 0; ky < 7; ++ky) {
            int iy = h + ky - 3;
            if (iy < 0 || iy >= HH) continue;
            float wt[7];
            #pragma unroll
            for (int kx = 0; kx < 7; ++kx)
                wt[kx] = kt[(ky * 7 + kx) * CC + c];
            float in[14];
            const float* qrow = qn + (size_t)iy * WW * CC;
            #pragma unroll
            for (int j = 0; j < 14; ++j) {
                int ix = w0 - 3 + j;
                in[j] = (ix >= 0 && ix < WW) ? qrow[(size_t)ix * CC] : 0.f;
            }
            #pragma unroll
            for (int i = 0; i < 8; ++i)
                #pragma unroll
                for (int kx = 0; kx < 7; ++kx)
                    acc[i] = fmaf(in[i + kx], wt[kx], acc[i]);
        }
    }

    // LayerNorm across 256 channels for each of 8 positions
    __shared__ float lsum[8][4];
    __shared__ float lsq[8][4];
    int lane = threadIdx.x & 63;
    int wv   = threadIdx.x >> 6;

    #pragma unroll
    for (int i = 0; i < 8; ++i) {
        float v  = acc[i];
        float v2 = v * v;
        #pragma unroll
        for (int m = 1; m < 64; m <<= 1) {
            v  += __shfl_xor(v,  m);
            v2 += __shfl_xor(v2, m);
        }
        if (lane == 0) { lsum[i][wv] = v; lsq[i][wv] = v2; }
    }
    __syncthreads();

    float lw = lnw[c];
    float lb = lnb[c];
    unsigned short* qo = qact + (((size_t)n * LQ) + (size_t)h * WW + w0) * CC + c;

    #pragma unroll
    for (int i = 0; i < 8; ++i) {
        float s  = lsum[i][0] + lsum[i][1] + lsum[i][2] + lsum[i][3];
        float s2 = lsq[i][0]  + lsq[i][1]  + lsq[i][2]  + lsq[i][3];
        float mu  = s * (1.0f / 256.0f);
        float var = s2 * (1.0f / 256.0f) - mu * mu;
        float inv = rsqrtf(var + 1e-5f);
        float yv  = (acc[i] - mu) * inv * lw + lb;
        qo[(size_t)i * CC] = f2bf(gelu_fast(yv));
    }
}

// -------------------------------------------------------------------------
// Kernel 2a: merged value + oa GEMM (bf16 MFMA), grid.y: 0,1=val  2=oa
// value: C(bf16, padded layout) = A * wt_val^T + bval
// oa   : C(f32, row-major 128)  = A * wt_oa^T  + b_oa
// -------------------------------------------------------------------------
__global__ __launch_bounds__(256) void gemm_val_oa(
    const unsigned short* __restrict__ A,
    const unsigned short* __restrict__ Bv, const float* __restrict__ bv_,
    unsigned short* __restrict__ Cv,
    const unsigned short* __restrict__ Bo, const float* __restrict__ bo_,
    float* __restrict__ Co)
{
    __shared__ unsigned short Al[128][72];
    __shared__ unsigned short Bl[128][72];

    bool oam = (blockIdx.y == 2);
    const unsigned short* Bt = oam ? Bo : Bv;
    const float* bias = oam ? bo_ : bv_;
    int bn = oam ? 0 : blockIdx.y * 128;

    int t    = threadIdx.x;
    int bm   = blockIdx.x * 128;
    int wid  = t >> 6;
    int lane = t & 63;
    int wr   = wid >> 1;
    int wc   = wid & 1;
    int lr   = lane & 15;
    int lg   = lane >> 4;

    int srow = t >> 1;
    int sseg = (t & 1) << 5;

    const unsigned short* gA = A + (size_t)(bm + srow) * 256 + sseg;
    const unsigned short* gB = Bt + (size_t)(bn + srow) * 256 + sseg;
    unsigned short* lA = &Al[srow][sseg];
    unsigned short* lB = &Bl[srow][sseg];

    f32x4 acc[4][4] = {};

    for (int kt = 0; kt < 4; ++kt) {
        const unsigned short* ga = gA + kt * 64;
        const unsigned short* gb = gB + kt * 64;
        u32x4 a0 = *(const u32x4*)(ga);
        u32x4 a1 = *(const u32x4*)(ga + 8);
        u32x4 a2 = *(const u32x4*)(ga + 16);
        u32x4 a3 = *(const u32x4*)(ga + 24);
        u32x4 b0 = *(const u32x4*)(gb);
        u32x4 b1 = *(const u32x4*)(gb + 8);
        u32x4 b2 = *(const u32x4*)(gb + 16);
        u32x4 b3 = *(const u32x4*)(gb + 24);
        *(u32x4*)(lA)      = a0;
        *(u32x4*)(lA + 8)  = a1;
        *(u32x4*)(lA + 16) = a2;
        *(u32x4*)(lA + 24) = a3;
        *(u32x4*)(lB)      = b0;
        *(u32x4*)(lB + 8)  = b1;
        *(u32x4*)(lB + 16) = b2;
        *(u32x4*)(lB + 24) = b3;
        __syncthreads();

        #pragma unroll
        for (int kk = 0; kk < 2; ++kk) {
            short8 af[4], bfr[4];
            #pragma unroll
            for (int m = 0; m < 4; ++m)
                af[m] = *(const short8*)(&Al[wr * 64 + m * 16 + lr][kk * 32 + lg * 8]);
            #pragma unroll
            for (int nn = 0; nn < 4; ++nn)
                bfr[nn] = *(const short8*)(&Bl[wc * 64 + nn * 16 + lr][kk * 32 + lg * 8]);
            #pragma unroll
            for (int m = 0; m < 4; ++m)
                #pragma unroll
                for (int nn = 0; nn < 4; ++nn)
                    acc[m][nn] = __builtin_amdgcn_mfma_f32_16x16x32_bf16(
                        af[m], bfr[nn], acc[m][nn], 0, 0, 0);
        }
        __syncthreads();
    }

    float bvv[4];
    #pragma unroll
    for (int nn = 0; nn < 4; ++nn) bvv[nn] = bias[bn + wc * 64 + nn * 16 + lr];

    #pragma unroll
    for (int m = 0; m < 4; ++m) {
        #pragma unroll
        for (int j = 0; j < 4; ++j) {
            int row = bm + wr * 64 + m * 16 + lg * 4 + j;
            if (oam) {
                size_t rbase = (size_t)row * 128;
                #pragma unroll
                for (int nn = 0; nn < 4; ++nn) {
                    int col = wc * 64 + nn * 16 + lr;
                    Co[rbase + col] = acc[m][nn][j] + bvv[nn];
                }
            } else {
                int nb = row >> 14;
                int hw = row & 16383;
                int hh = hw >> 7;
                int ww = hw & 127;
                size_t rbase = (((size_t)nb * HPP + (hh + 1)) * WPP + (ww + 1)) * CC;
                #pragma unroll
                for (int nn = 0; nn < 4; ++nn) {
                    int col = bn + wc * 64 + nn * 16 + lr;
                    Cv[rbase + col] = f2bf(acc[m][nn][j] + bvv[nn]);
                }
            }
        }
    }
}

// -------------------------------------------------------------------------
// Kernel 2b: bf16 MFMA GEMM, row-major fp32 store (output GEMM)
// -------------------------------------------------------------------------
__global__ __launch_bounds__(256) void gemm_mfma_row(
    const unsigned short* __restrict__ A,
    const unsigned short* __restrict__ Bt,
    const float* __restrict__ bias,
    float* __restrict__ C,
    int Nn)
{
    __shared__ unsigned short Al[128][72];
    __shared__ unsigned short Bl[128][72];

    int t    = threadIdx.x;
    int bm   = blockIdx.x * 128;
    int bn   = blockIdx.y * 128;
    int wid  = t >> 6;
    int lane = t & 63;
    int wr   = wid >> 1;
    int wc   = wid & 1;
    int lr   = lane & 15;
    int lg   = lane >> 4;

    int srow = t >> 1;
    int sseg = (t & 1) << 5;

    const unsigned short* gA = A + (size_t)(bm + srow) * 256 + sseg;
    const unsigned short* gB = Bt + (size_t)(bn + srow) * 256 + sseg;
    unsigned short* lA = &Al[srow][sseg];
    unsigned short* lB = &Bl[srow][sseg];

    f32x4 acc[4][4] = {};

    for (int kt = 0; kt < 4; ++kt) {
        const unsigned short* ga = gA + kt * 64;
        const unsigned short* gb = gB + kt * 64;
        u32x4 a0 = *(const u32x4*)(ga);
        u32x4 a1 = *(const u32x4*)(ga + 8);
        u32x4 a2 = *(const u32x4*)(ga + 16);
        u32x4 a3 = *(const u32x4*)(ga + 24);
        u32x4 b0 = *(const u32x4*)(gb);
        u32x4 b1 = *(const u32x4*)(gb + 8);
        u32x4 b2 = *(const u32x4*)(gb + 16);
        u32x4 b3 = *(const u32x4*)(gb + 24);
        *(u32x4*)(lA)      = a0;
        *(u32x4*)(lA + 8)  = a1;
        *(u32x4*)(lA + 16) = a2;
        *(u32x4*)(lA + 24) = a3;
        *(u32x4*)(lB)      = b0;
        *(u32x4*)(lB + 8)  = b1;
        *(u32x4*)(lB + 16) = b2;
        *(u32x4*)(lB + 24) = b3;
        __syncthreads();

        #pragma unroll
        for (int kk = 0; kk < 2; ++kk) {
            short8 af[4], bfr[4];
            #pragma unroll
            for (int m = 0; m < 4; ++m)
                af[m] = *(const short8*)(&Al[wr * 64 + m * 16 + lr][kk * 32 + lg * 8]);
            #pragma unroll
            for (int nn = 0; nn < 4; ++nn)
                bfr[nn] = *(const short8*)(&Bl[wc * 64 + nn * 16 + lr][kk * 32 + lg * 8]);
            #pragma unroll
            for (int m = 0; m < 4; ++m)
                #pragma unroll
                for (int nn = 0; nn < 4; ++nn)
                    acc[m][nn] = __builtin_amdgcn_mfma_f32_16x16x32_bf16(
                        af[m], bfr[nn], acc[m][nn], 0, 0, 0);
        }
        __syncthreads();
    }

    float bvv[4];
    #pragma unroll
    for (int nn = 0; nn < 4; ++nn) bvv[nn] = bias[bn + wc * 64 + nn * 16 + lr];

    #pragma unroll
    for (int m = 0; m < 4; ++m) {
        #pragma unroll
        for (int j = 0; j < 4; ++j) {
            int row = bm + wr * 64 + m * 16 + lg * 4 + j;
            size_t rbase = (size_t)row * Nn;
            #pragma unroll
            for (int nn = 0; nn < 4; ++nn) {
                int col = bn + wc * 64 + nn * 16 + lr;
                C[rbase + col] = acc[m][nn][j] + bvv[nn];
            }
        }
    }
}

// -------------------------------------------------------------------------
// Kernel 3: deformable bilinear sampling + attention-weighted sum
// v_pad is bf16: gathers are ushort4 (8B), halving L2/HBM gather traffic.
// -------------------------------------------------------------------------
__global__ __launch_bounds__(256) void sampler_kernel(
    const float* __restrict__ rp,            // (N, LQ, 1, 2)
    const float* __restrict__ oa,            // (N*LQ, 128)
    const unsigned short* __restrict__ vpad, // (N, HP, WP, C) bf16
    unsigned short* __restrict__ outb)       // (N*LQ, C) bf16
{
    __shared__ int4   sIdx[4][4][8];
    __shared__ float4 sW[4][4][8];

    int tid  = threadIdx.x;
    int row0 = blockIdx.x * 4;

    if (tid < 128) {
        int rl   = tid >> 5;
        int hp   = tid & 31;
        int head = hp >> 2;
        int p    = hp & 3;
        int row  = row0 + rl;

        float ref0 = rp[(size_t)row * 2 + 0];
        float ref1 = rp[(size_t)row * 2 + 1];
        float o0 = oa[(size_t)row * 128 + head * 8 + p * 2 + 0];
        float o1 = oa[(size_t)row * 128 + head * 8 + p * 2 + 1];
        float al = oa[(size_t)row * 128 + 64 + head * 4 + p];
        float a  = 1.0f / (1.0f + __builtin_amdgcn_exp2f(-al * 1.4426950409f));

        float gy = (float)(p >> 1);
        float gx = (float)(p & 1);
        float x = ref0 * WPP + gy + o0 - 0.5f;
        float y = ref1 * HPP + gx + o1 - 0.5f;

        float x0f = floorf(x), y0f = floorf(y);
        int   x0  = (int)x0f,  y0  = (int)y0f;
        float wx1 = x - x0f, wx0 = 1.f - wx1;
        float wy1 = y - y0f, wy0 = 1.f - wy1;
        int x1 = x0 + 1, y1 = y0 + 1;

        bool vx0 = (x0 >= 0) & (x0 < WPP);
        bool vx1 = (x1 >= 0) & (x1 < WPP);
        bool vy0 = (y0 >= 0) & (y0 < HPP);
        bool vy1 = (y1 >= 0) & (y1 < HPP);
        int cx0 = min(max(x0, 0), WPP - 1);
        int cx1 = min(max(x1, 0), WPP - 1);
        int cy0 = min(max(y0, 0), HPP - 1);
        int cy1 = min(max(y1, 0), HPP - 1);

        int4 id;
        id.x = cy0 * WPP + cx0;
        id.y = cy0 * WPP + cx1;
        id.z = cy1 * WPP + cx0;
        id.w = cy1 * WPP + cx1;
        float4 w;
        w.x = (vx0 && vy0) ? a * wx0 * wy0 : 0.f;
        w.y = (vx1 && vy0) ? a * wx1 * wy0 : 0.f;
        w.z = (vx0 && vy1) ? a * wx0 * wy1 : 0.f;
        w.w = (vx1 && vy1) ? a * wx1 * wy1 : 0.f;

        sIdx[rl][p][head] = id;
        sW[rl][p][head]   = w;
    }
    __syncthreads();

    int rl   = tid >> 6;
    int c0   = (tid & 63) * 4;
    int head = c0 >> 5;
    int row  = row0 + rl;
    int n    = row >> 14;
    const unsigned short* vbase = vpad + (size_t)n * HPP * WPP * CC + c0;

    float4 acc = make_float4(0.f, 0.f, 0.f, 0.f);
    #pragma unroll
    for (int p = 0; p < 4; ++p) {
        int4   id = sIdx[rl][p][head];
        float4 w  = sW[rl][p][head];
        ushort4 g0 = *reinterpret_cast<const ushort4*>(vbase + (size_t)id.x * CC);
        ushort4 g1 = *reinterpret_cast<const ushort4*>(vbase + (size_t)id.y * CC);
        ushort4 g2 = *reinterpret_cast<const ushort4*>(vbase + (size_t)id.z * CC);
        ushort4 g3 = *reinterpret_cast<const ushort4*>(vbase + (size_t)id.w * CC);
        acc.x += w.x * bf2f(g0.x) + w.y * bf2f(g1.x) + w.z * bf2f(g2.x) + w.w * bf2f(g3.x);
        acc.y += w.x * bf2f(g0.y) + w.y * bf2f(g1.y) + w.z * bf2f(g2.y) + w.w * bf2f(g3.y);
        acc.z += w.x * bf2f(g0.z) + w.y * bf2f(g1.z) + w.z * bf2f(g2.z) + w.w * bf2f(g3.z);
        acc.w += w.x * bf2f(g0.w) + w.y * bf2f(g1.w) + w.z * bf2f(g2.w) + w.w * bf2f(g3.w);
    }
    ushort4 o;
    o.x = f2bf(acc.x);
    o.y = f2bf(acc.y);
    o.z = f2bf(acc.z);
    o.w = f2bf(acc.w);
    *reinterpret_cast<ushort4*>(&outb[(size_t)row * CC + c0]) = o;
}

// -------------------------------------------------------------------------
extern "C" void kernel_launch(void* const* d_in, const int* in_sizes, int n_in,
                              void* d_out, int out_size, void* d_ws, size_t ws_size,
                              hipStream_t stream)
{
    const float* query = (const float*)d_in[0];
    const float* rp    = (const float*)d_in[1];
    const float* dwk   = (const float*)d_in[4];
    const float* dwb   = (const float*)d_in[5];
    const float* lnw   = (const float*)d_in[6];
    const float* lnb   = (const float*)d_in[7];
    const float* Woff  = (const float*)d_in[8];
    const float* boff  = (const float*)d_in[9];
    const float* Wattn = (const float*)d_in[10];
    const float* battn = (const float*)d_in[11];
    const float* Wval  = (const float*)d_in[12];
    const float* bval  = (const float*)d_in[13];
    const float* Wout  = (const float*)d_in[14];
    const float* bout  = (const float*)d_in[15];
    float* out = (float*)d_out;

    const int M = NB * LQ;  // 32768

    // workspace layout (bytes)
    uint8_t* w8 = (uint8_t*)d_ws;
    unsigned short* q_act  = (unsigned short*)w8;                 // 16,777,216
    unsigned short* v_pad  = (unsigned short*)(w8 + 16777216);    // 17,305,600 (bf16)
    float*          oa     = (float*)(w8 + 34082816);             // 16,777,216
    unsigned short* wt_val = (unsigned short*)(w8 + 50860032);    //    131,072
    unsigned short* wt_out = (unsigned short*)(w8 + 50991104);    //    131,072
    unsigned short* wt_oa  = (unsigned short*)(w8 + 51122176);    //     65,536
    float*          b_oa   = (float*)(w8 + 51187712);             //        512
    float*          kt     = (float*)(w8 + 51188224);             //     50,176
    unsigned short* out_attn = q_act;  // alias: q_act dead after oa GEMM

    // border-only zeroing of v_pad (interior fully written by value GEMM)
    zero_border_kernel<<<1032, 256, 0, stream>>>(v_pad);

    // merged weight prep
    prep_kernel<<<817, 256, 0, stream>>>(
        dwk, Wval, Wout, Woff, boff, Wattn, battn,
        kt, wt_val, wt_out, wt_oa, b_oa);

    // conv + LN + GELU -> bf16 q_act
    {
        dim3 grid(WW / 8, HH, NB);
        conv_ln_gelu_kernel<<<grid, 256, 0, stream>>>(
            query, kt, dwb, lnw, lnb, q_act);
    }

    // value GEMM (padded bf16 layout) + oa GEMM, one launch
    {
        dim3 grid(M / 128, 3);
        gemm_val_oa<<<grid, 256, 0, stream>>>(
            q_act, wt_val, bval, v_pad, wt_oa, b_oa, oa);
    }

    // sampling + weighted sum -> bf16
    sampler_kernel<<<M / 4, 256, 0, stream>>>(rp, oa, v_pad, out_attn);

    // output GEMM -> d_out fp32
    {
        dim3 grid(M / 128, 2);
        gemm_mfma_row<<<grid, 256, 0, stream>>>(out_attn, wt_out, bout, out, 256);
    }
}